// Round 1
// baseline (27255.597 us; speedup 1.0000x reference)
//
#include <hip/hip_runtime.h>

typedef __bf16 bf16_t;
typedef __bf16 bf16x8 __attribute__((ext_vector_type(8)));
typedef float  f32x4  __attribute__((ext_vector_type(4)));

#define T_STEPS 1024

__device__ __forceinline__ float sigm_f(float x) {
  float e = __builtin_amdgcn_exp2f(x * -1.44269504f);
  return __builtin_amdgcn_rcpf(1.0f + e);
}
__device__ __forceinline__ float tanh_f(float x) {
  x = fminf(fmaxf(x, -30.0f), 30.0f);
  float e = __builtin_amdgcn_exp2f(x * -2.88539008f);
  float r = __builtin_amdgcn_rcpf(1.0f + e);
  return fmaf(-2.0f * e, r, 1.0f);   // (1-e)/(1+e) = 1 - 2e/(1+e)
}

// ---------------------------------------------------------------- casts
__global__ void cast_f32_to_bf16(const float* __restrict__ src,
                                 bf16_t* __restrict__ dst, long n8) {
  long i = (long)blockIdx.x * blockDim.x + threadIdx.x;
  long stride = (long)gridDim.x * blockDim.x;
  for (; i < n8; i += stride) {
    const float4* sp = (const float4*)src + 2 * i;
    float4 a = sp[0], b = sp[1];
    bf16x8 v;
    v[0] = (bf16_t)a.x; v[1] = (bf16_t)a.y; v[2] = (bf16_t)a.z; v[3] = (bf16_t)a.w;
    v[4] = (bf16_t)b.x; v[5] = (bf16_t)b.y; v[6] = (bf16_t)b.z; v[7] = (bf16_t)b.w;
    ((bf16x8*)dst)[i] = v;
  }
}

// ---------------------------------------------------------------- xg GEMM
// C[row][g] = bf16( sum_k A[row][k]*Bw[g][k] + bias[g] )
// A: [262144][K] bf16, Bw: [768][K] bf16 (row-major = B^T), C: [262144][768] bf16
__global__ __launch_bounds__(256) void gemm_xg(
    const bf16_t* __restrict__ A, const bf16_t* __restrict__ Bw,
    const float* __restrict__ bias, bf16_t* __restrict__ C, int K) {
  __shared__ bf16_t As[128 * 64];
  __shared__ bf16_t Bs[128 * 64];
  const int tid = threadIdx.x;
  const int w = tid >> 6, ln = tid & 63;
  const int lq = ln >> 4, lr = ln & 15;
  const int wr = w >> 1, wc = w & 1;
  const size_t am0 = (size_t)blockIdx.y * 128;
  const int bn0 = blockIdx.x * 128;

  f32x4 acc[4][4];
  f32x4 zf = {0.f, 0.f, 0.f, 0.f};
#pragma unroll
  for (int i = 0; i < 4; ++i)
#pragma unroll
    for (int j = 0; j < 4; ++j) acc[i][j] = zf;

  for (int kb = 0; kb < K; kb += 64) {
    // stage A,B tiles: linear LDS dest, inverse-swizzled global source
#pragma unroll
    for (int c = 0; c < 4; ++c) {
      int rl = w * 32 + c * 8 + (ln >> 3);          // local row 0..127
      int cb = ((ln & 7) * 16) ^ ((rl & 7) << 4);   // logical col-byte 0..127
      const bf16_t* ga = A + (am0 + rl) * K + kb + (cb >> 1);
      __builtin_amdgcn_global_load_lds(
          (const __attribute__((address_space(1))) void*)ga,
          (__attribute__((address_space(3))) void*)((char*)As + (w * 32 + c * 8) * 128),
          16, 0, 0);
      const bf16_t* gb = Bw + (size_t)(bn0 + rl) * K + kb + (cb >> 1);
      __builtin_amdgcn_global_load_lds(
          (const __attribute__((address_space(1))) void*)gb,
          (__attribute__((address_space(3))) void*)((char*)Bs + (w * 32 + c * 8) * 128),
          16, 0, 0);
    }
    __syncthreads();
#pragma unroll
    for (int ks = 0; ks < 2; ++ks) {
      bf16x8 av[4], bv[4];
#pragma unroll
      for (int mi = 0; mi < 4; ++mi) {
        int row = wr * 64 + mi * 16 + lr;
        int cb = (ks * 64 + lq * 16) ^ ((row & 7) << 4);
        av[mi] = *(const bf16x8*)((const char*)As + row * 128 + cb);
      }
#pragma unroll
      for (int ni = 0; ni < 4; ++ni) {
        int row = wc * 64 + ni * 16 + lr;
        int cb = (ks * 64 + lq * 16) ^ ((row & 7) << 4);
        bv[ni] = *(const bf16x8*)((const char*)Bs + row * 128 + cb);
      }
#pragma unroll
      for (int mi = 0; mi < 4; ++mi)
#pragma unroll
        for (int ni = 0; ni < 4; ++ni)
          acc[mi][ni] = __builtin_amdgcn_mfma_f32_16x16x32_bf16(
              av[mi], bv[ni], acc[mi][ni], 0, 0, 0);
    }
    __syncthreads();
  }
#pragma unroll
  for (int ni = 0; ni < 4; ++ni) {
    int g = bn0 + wc * 64 + ni * 16 + lr;
    float bi = bias[g];
#pragma unroll
    for (int mi = 0; mi < 4; ++mi) {
#pragma unroll
      for (int r = 0; r < 4; ++r) {
        size_t row = am0 + wr * 64 + mi * 16 + lq * 4 + r;
        C[row * 768 + g] = (bf16_t)(acc[mi][ni][r] + bi);
      }
    }
  }
}

// ---------------------------------------------------------------- GRU scan
// One WG = 16 batch rows, full Whh register-resident, 1024 steps.
// 8 waves; wave w owns hidden slice j in [32w, 32w+32).
__global__ __launch_bounds__(512, 2) void gru_scan(
    const bf16_t* __restrict__ xg,   // [T*256][768] (bih already added)
    const bf16_t* __restrict__ whh,  // [768][256]
    const float* __restrict__ bhh,   // [768]
    const float* __restrict__ h0,    // [256][256]
    bf16_t* __restrict__ outb,       // bf16 out (layers 0..4) or null
    float* __restrict__ outf) {      // fp32 out (layer 5) or null
  __shared__ bf16_t hs[16 * 256];    // h as MFMA-A source, XOR-swizzled
  const int tid = threadIdx.x;
  const int w = tid >> 6, ln = tid & 63;
  const int lq = ln >> 4, lr = ln & 15;
  const int b0 = blockIdx.x * 16;
  const int jb = w * 32 + lr;        // j for p=0; p=1 adds 16

  // B-fragments of Whh: u = gate*2+p, gtile g-base = gate*256 + w*32 + p*16
  bf16x8 wf[6][8];
  float bh[6];
#pragma unroll
  for (int u = 0; u < 6; ++u) {
    const int gate = u >> 1, p = u & 1;
    const int g = gate * 256 + w * 32 + p * 16 + lr;
    bh[u] = bhh[g];
#pragma unroll
    for (int kt = 0; kt < 8; ++kt)
      wf[u][kt] = *(const bf16x8*)(whh + g * 256 + kt * 32 + lq * 8);
  }

  // fp32 h state in regs: lane owns (b = 4*lq+r, j = jb + 16p)
  float h[2][4];
#pragma unroll
  for (int p = 0; p < 2; ++p)
#pragma unroll
    for (int r = 0; r < 4; ++r) {
      const int bl = lq * 4 + r;
      const int j = jb + p * 16;
      float v = h0[(size_t)(b0 + bl) * 256 + j];
      h[p][r] = v;
      hs[bl * 256 + (((j >> 3) ^ (bl & 7)) << 3) + (j & 7)] = (bf16_t)v;
    }

  const bf16_t* xgp = xg + (size_t)b0 * 768;
  bf16_t* obp = outb ? outb + (size_t)b0 * 256 : (bf16_t*)0;
  float* ofp = outf ? outf + (size_t)b0 * 256 : (float*)0;

  for (int t = 0; t < T_STEPS; ++t) {
    __syncthreads();  // hs(t) stable for everyone
    // preload xg for p=0 (hides global latency under MFMA)
    float xv0[3][4];
#pragma unroll
    for (int gt = 0; gt < 3; ++gt)
#pragma unroll
      for (int r = 0; r < 4; ++r)
        xv0[gt][r] = (float)xgp[(size_t)t * 196608 + (lq * 4 + r) * 768 + gt * 256 + jb];

    f32x4 acc[6];
    f32x4 zf = {0.f, 0.f, 0.f, 0.f};
#pragma unroll
    for (int u = 0; u < 6; ++u) acc[u] = zf;
#pragma unroll
    for (int kt = 0; kt < 8; ++kt) {
      const bf16x8 a =
          *(const bf16x8*)&hs[lr * 256 + (((kt * 4 + lq) ^ (lr & 7)) << 3)];
#pragma unroll
      for (int u = 0; u < 6; ++u)
        acc[u] = __builtin_amdgcn_mfma_f32_16x16x32_bf16(a, wf[u][kt], acc[u], 0, 0, 0);
    }
    __syncthreads();  // all A-reads done; hs writable
    // p=1 xg loads: latency hidden behind p=0 gate math
    float xv1[3][4];
#pragma unroll
    for (int gt = 0; gt < 3; ++gt)
#pragma unroll
      for (int r = 0; r < 4; ++r)
        xv1[gt][r] =
            (float)xgp[(size_t)t * 196608 + (lq * 4 + r) * 768 + gt * 256 + jb + 16];

#pragma unroll
    for (int p = 0; p < 2; ++p) {
#pragma unroll
      for (int r = 0; r < 4; ++r) {
        const int bl = lq * 4 + r;
        const int j = jb + p * 16;
        const float xr = p ? xv1[0][r] : xv0[0][r];
        const float xz = p ? xv1[1][r] : xv0[1][r];
        const float xn = p ? xv1[2][r] : xv0[2][r];
        const float rg = sigm_f(xr + acc[0 + p][r] + bh[0 + p]);
        const float zg = sigm_f(xz + acc[2 + p][r] + bh[2 + p]);
        const float nn = tanh_f(xn + rg * (acc[4 + p][r] + bh[4 + p]));
        const float hv = nn + zg * (h[p][r] - nn);
        h[p][r] = hv;
        hs[bl * 256 + (((j >> 3) ^ (bl & 7)) << 3) + (j & 7)] = (bf16_t)hv;
        const size_t oi = (size_t)t * 65536 + bl * 256 + j;
        if (obp) obp[oi] = (bf16_t)hv;
        else     ofp[oi] = hv;
      }
    }
  }
}

// ---------------------------------------------------------------- launch
extern "C" void kernel_launch(void* const* d_in, const int* in_sizes, int n_in,
                              void* d_out, int out_size, void* d_ws, size_t ws_size,
                              hipStream_t stream) {
  const float* x    = (const float*)d_in[0];
  const float* h0   = (const float*)d_in[1];
  const float* wih0 = (const float*)d_in[2];
  const float* wih  = (const float*)d_in[3];
  const float* whh  = (const float*)d_in[4];
  const float* bih  = (const float*)d_in[5];
  const float* bhh  = (const float*)d_in[6];

  // ws layout (bytes): xg[402,653,184] | whh_bf[2,359,296] | wih0_bf[196,608]
  //                    | wih_bf[1,966,080] | x_bf[67,108,864]  (~452 MB)
  char* ws = (char*)d_ws;
  bf16_t* xg      = (bf16_t*)(ws);
  bf16_t* whh_bf  = (bf16_t*)(ws + 402653184ull);
  bf16_t* wih0_bf = (bf16_t*)(ws + 405012480ull);
  bf16_t* wih_bf  = (bf16_t*)(ws + 405209088ull);
  bf16_t* x_bf    = (bf16_t*)(ws + 407175168ull);

  cast_f32_to_bf16<<<2048, 256, 0, stream>>>(x, x_bf, 4194304L);
  cast_f32_to_bf16<<<576, 256, 0, stream>>>(whh, whh_bf, 147456L);
  cast_f32_to_bf16<<<48, 256, 0, stream>>>(wih0, wih0_bf, 12288L);
  cast_f32_to_bf16<<<480, 256, 0, stream>>>(wih, wih_bf, 122880L);

  // intermediate layer sequences ping/pong inside d_out (bf16 halves);
  // both are dead before the final fp32 write of layer 5 overwrites d_out.
  bf16_t* P0 = (bf16_t*)d_out;
  bf16_t* P1 = P0 + 67108864ull;  // elements (134,217,728 B offset)
  float* OF = (float*)d_out;

  const bf16_t* inl = x_bf;
  int K = 128;
  const bf16_t* W = wih0_bf;
  bf16_t* outs[6] = {P0, P1, P0, P1, P0, nullptr};

  for (int l = 0; l < 6; ++l) {
    gemm_xg<<<dim3(6, 2048), 256, 0, stream>>>(inl, W, bih + l * 768, xg, K);
    gru_scan<<<16, 512, 0, stream>>>(xg, whh_bf + (size_t)l * 196608,
                                     bhh + l * 768, h0 + (size_t)l * 65536,
                                     outs[l], l == 5 ? OF : nullptr);
    inl = outs[l];
    K = 256;
    W = wih_bf + (size_t)l * 196608;  // layer l+1 uses w_ih[l]
  }
}

// Round 2
// 22078.835 us; speedup vs baseline: 1.2345x; 1.2345x over previous
//
#include <hip/hip_runtime.h>

typedef __bf16 bf16_t;
typedef __bf16 bf16x4 __attribute__((ext_vector_type(4)));
typedef __bf16 bf16x8 __attribute__((ext_vector_type(8)));
typedef float  f32x4  __attribute__((ext_vector_type(4)));

__device__ __forceinline__ float sigm_f(float x) {
  float e = __builtin_amdgcn_exp2f(x * -1.44269504f);
  return __builtin_amdgcn_rcpf(1.0f + e);
}
__device__ __forceinline__ float tanh_f(float x) {
  x = fminf(fmaxf(x, -15.0f), 15.0f);
  float e = __builtin_amdgcn_exp2f(x * -2.88539008f);
  float r = __builtin_amdgcn_rcpf(1.0f + e);
  return fmaf(-2.0f * e, r, 1.0f);   // (1-e)/(1+e)
}

// ---------------------------------------------------------------- casts
__global__ void cast_f32_to_bf16(const float* __restrict__ src,
                                 bf16_t* __restrict__ dst, long n8) {
  long i = (long)blockIdx.x * blockDim.x + threadIdx.x;
  long stride = (long)gridDim.x * blockDim.x;
  for (; i < n8; i += stride) {
    const float4* sp = (const float4*)src + 2 * i;
    float4 a = sp[0], b = sp[1];
    bf16x8 v;
    v[0] = (bf16_t)a.x; v[1] = (bf16_t)a.y; v[2] = (bf16_t)a.z; v[3] = (bf16_t)a.w;
    v[4] = (bf16_t)b.x; v[5] = (bf16_t)b.y; v[6] = (bf16_t)b.z; v[7] = (bf16_t)b.w;
    ((bf16x8*)dst)[i] = v;
  }
}

// ---------------------------------------------------------------- xg GEMM
// Writes xg TRANSPOSED for the scan: xgT[((t*16+s)*768+g)*16 + bl], bl=b&15,
// s=b>>4.  bias = bih[g] + (g<512 ? bhh[g] : 0)  (bhh of n-gate applied in scan).
__global__ __launch_bounds__(256) void gemm_xg(
    const bf16_t* __restrict__ A, const bf16_t* __restrict__ Bw,
    const float* __restrict__ bih, const float* __restrict__ bhh,
    bf16_t* __restrict__ C, int K) {
  __shared__ bf16_t As[128 * 64];
  __shared__ bf16_t Bs[128 * 64];
  const int tid = threadIdx.x;
  const int w = tid >> 6, ln = tid & 63;
  const int lq = ln >> 4, lr = ln & 15;
  const int wr = w >> 1, wc = w & 1;
  const size_t am0 = (size_t)blockIdx.y * 128;
  const int bn0 = blockIdx.x * 128;

  f32x4 acc[4][4];
  f32x4 zf = {0.f, 0.f, 0.f, 0.f};
#pragma unroll
  for (int i = 0; i < 4; ++i)
#pragma unroll
    for (int j = 0; j < 4; ++j) acc[i][j] = zf;

  for (int kb = 0; kb < K; kb += 64) {
#pragma unroll
    for (int c = 0; c < 4; ++c) {
      int rl = w * 32 + c * 8 + (ln >> 3);
      int cb = ((ln & 7) * 16) ^ ((rl & 7) << 4);
      const bf16_t* ga = A + (am0 + rl) * K + kb + (cb >> 1);
      __builtin_amdgcn_global_load_lds(
          (const __attribute__((address_space(1))) void*)ga,
          (__attribute__((address_space(3))) void*)((char*)As + (w * 32 + c * 8) * 128),
          16, 0, 0);
      const bf16_t* gb = Bw + (size_t)(bn0 + rl) * K + kb + (cb >> 1);
      __builtin_amdgcn_global_load_lds(
          (const __attribute__((address_space(1))) void*)gb,
          (__attribute__((address_space(3))) void*)((char*)Bs + (w * 32 + c * 8) * 128),
          16, 0, 0);
    }
    __syncthreads();
#pragma unroll
    for (int ks = 0; ks < 2; ++ks) {
      bf16x8 av[4], bv[4];
#pragma unroll
      for (int mi = 0; mi < 4; ++mi) {
        int row = wr * 64 + mi * 16 + lr;
        int cb = (ks * 64 + lq * 16) ^ ((row & 7) << 4);
        av[mi] = *(const bf16x8*)((const char*)As + row * 128 + cb);
      }
#pragma unroll
      for (int ni = 0; ni < 4; ++ni) {
        int row = wc * 64 + ni * 16 + lr;
        int cb = (ks * 64 + lq * 16) ^ ((row & 7) << 4);
        bv[ni] = *(const bf16x8*)((const char*)Bs + row * 128 + cb);
      }
#pragma unroll
      for (int mi = 0; mi < 4; ++mi)
#pragma unroll
        for (int ni = 0; ni < 4; ++ni)
          acc[mi][ni] = __builtin_amdgcn_mfma_f32_16x16x32_bf16(
              av[mi], bv[ni], acc[mi][ni], 0, 0, 0);
    }
    __syncthreads();
  }
#pragma unroll
  for (int ni = 0; ni < 4; ++ni) {
    int g = bn0 + wc * 64 + ni * 16 + lr;
    float bi = bih[g] + (g < 512 ? bhh[g] : 0.0f);
#pragma unroll
    for (int mi = 0; mi < 4; ++mi) {
      size_t row = am0 + wr * 64 + mi * 16 + lq * 4;  // +r, r=0..3
      int t = (int)(row >> 8);
      int b = (int)(row & 255);
      int s = b >> 4, bl = b & 15;
      bf16x4 v;
#pragma unroll
      for (int r = 0; r < 4; ++r) v[r] = (bf16_t)(acc[mi][ni][r] + bi);
      *(bf16x4*)&C[(((size_t)t * 16 + s) * 768 + g) * 16 + bl] = v;
    }
  }
}

// ---------------------------------------------------------------- GRU scan
// 16 WGs x 1024 threads (16 waves, 4 waves/SIMD, 128-VGPR cap).
// Wave w owns j-tile [16w,16w+16); per-lane Whh fragments = 96 VGPRs.
// Lane (lq,lr): j = 16w+lr, batch rows bl = 4lq..4lq+3. fp32 h in regs.
template <int FINAL>
__global__ __launch_bounds__(1024, 4) void gru_scan(
    const bf16_t* __restrict__ xg,   // xgT [1024][16][768][16]
    const bf16_t* __restrict__ whh,  // [768][256]
    const float* __restrict__ bhh,   // [768] (n-gate part used here)
    const float* __restrict__ h0,    // [256][256]
    void* __restrict__ outv) {
  __shared__ bf16_t hs[16 * 256];    // XOR-swizzled h (MFMA A source)
  const int tid = threadIdx.x;
  const int w = tid >> 6, ln = tid & 63;
  const int lq = ln >> 4, lr = ln & 15;
  const int s = blockIdx.x;
  const int j = w * 16 + lr;

  bf16x8 wf[3][8];
#pragma unroll
  for (int gt = 0; gt < 3; ++gt) {
    const int g = gt * 256 + j;
#pragma unroll
    for (int kt = 0; kt < 8; ++kt)
      wf[gt][kt] = *(const bf16x8*)(whh + (size_t)g * 256 + kt * 32 + lq * 8);
  }
  const float bhn = bhh[512 + j];

  float h[4];
#pragma unroll
  for (int r = 0; r < 4; ++r) {
    const int bl = lq * 4 + r;
    const float v = h0[(size_t)(s * 16 + bl) * 256 + j];
    h[r] = v;
    hs[bl * 256 + ((((j >> 3) ^ (bl & 7)) << 3) | (j & 7))] = (bf16_t)v;
  }

  const bf16_t* xgp = xg + (size_t)s * 12288 + j * 16 + lq * 4;
  const size_t obase = (size_t)(s * 16 + lq * 4) * 256 + j;
  bf16_t* ob = (bf16_t*)outv + obase;
  float*  of = (float*)outv + obase;

  for (int t = 0; t < 1024; ++t) {
    __syncthreads();                       // hs(t-1) complete everywhere
    const bf16x4 xv0 = *(const bf16x4*)(xgp);
    const bf16x4 xv1 = *(const bf16x4*)(xgp + 4096);
    const bf16x4 xv2 = *(const bf16x4*)(xgp + 8192);
    f32x4 acc0 = {0.f, 0.f, 0.f, 0.f};
    f32x4 acc1 = {0.f, 0.f, 0.f, 0.f};
    f32x4 acc2 = {0.f, 0.f, 0.f, 0.f};
#pragma unroll
    for (int kt = 0; kt < 8; ++kt) {
      const bf16x8 a =
          *(const bf16x8*)&hs[lr * 256 + (((kt * 4 + lq) ^ (lr & 7)) << 3)];
      acc0 = __builtin_amdgcn_mfma_f32_16x16x32_bf16(a, wf[0][kt], acc0, 0, 0, 0);
      acc1 = __builtin_amdgcn_mfma_f32_16x16x32_bf16(a, wf[1][kt], acc1, 0, 0, 0);
      acc2 = __builtin_amdgcn_mfma_f32_16x16x32_bf16(a, wf[2][kt], acc2, 0, 0, 0);
    }
    __syncthreads();                       // all A-reads done; hs writable
#pragma unroll
    for (int r = 0; r < 4; ++r) {
      const int bl = lq * 4 + r;
      const float rg = sigm_f((float)xv0[r] + acc0[r]);   // biases pre-folded
      const float zg = sigm_f((float)xv1[r] + acc1[r]);
      const float nn = tanh_f((float)xv2[r] + rg * (acc2[r] + bhn));
      const float hv = nn + zg * (h[r] - nn);
      h[r] = hv;
      hs[bl * 256 + ((((j >> 3) ^ (bl & 7)) << 3) | (j & 7))] = (bf16_t)hv;
      if (FINAL) of[(size_t)t * 65536 + r * 256] = hv;
      else       ob[(size_t)t * 65536 + r * 256] = (bf16_t)hv;
    }
    xgp += 196608;
  }
}

// ---------------------------------------------------------------- launch
extern "C" void kernel_launch(void* const* d_in, const int* in_sizes, int n_in,
                              void* d_out, int out_size, void* d_ws, size_t ws_size,
                              hipStream_t stream) {
  const float* x    = (const float*)d_in[0];
  const float* h0   = (const float*)d_in[1];
  const float* wih0 = (const float*)d_in[2];
  const float* wih  = (const float*)d_in[3];
  const float* whh  = (const float*)d_in[4];
  const float* bih  = (const float*)d_in[5];
  const float* bhh  = (const float*)d_in[6];

  // ws layout (bytes): xgT[402,653,184] | whh_bf | wih0_bf | wih_bf | x_bf
  char* ws = (char*)d_ws;
  bf16_t* xgT     = (bf16_t*)(ws);
  bf16_t* whh_bf  = (bf16_t*)(ws + 402653184ull);
  bf16_t* wih0_bf = (bf16_t*)(ws + 405012480ull);
  bf16_t* wih_bf  = (bf16_t*)(ws + 405209088ull);
  bf16_t* x_bf    = (bf16_t*)(ws + 407175168ull);

  cast_f32_to_bf16<<<2048, 256, 0, stream>>>(x, x_bf, 4194304L);
  cast_f32_to_bf16<<<576, 256, 0, stream>>>(whh, whh_bf, 147456L);
  cast_f32_to_bf16<<<48, 256, 0, stream>>>(wih0, wih0_bf, 12288L);
  cast_f32_to_bf16<<<480, 256, 0, stream>>>(wih, wih_bf, 122880L);

  // intermediate layer sequences ping/pong inside d_out (bf16 halves)
  bf16_t* P0 = (bf16_t*)d_out;
  bf16_t* P1 = P0 + 67108864ull;
  float* OF = (float*)d_out;

  const bf16_t* inl = x_bf;
  int K = 128;
  const bf16_t* W = wih0_bf;
  bf16_t* outs[5] = {P0, P1, P0, P1, P0};

  for (int l = 0; l < 6; ++l) {
    gemm_xg<<<dim3(6, 2048), 256, 0, stream>>>(inl, W, bih + l * 768,
                                               bhh + l * 768, xgT, K);
    if (l < 5)
      gru_scan<0><<<16, 1024, 0, stream>>>(xgT, whh_bf + (size_t)l * 196608,
                                           bhh + l * 768, h0 + (size_t)l * 65536,
                                           (void*)outs[l]);
    else
      gru_scan<1><<<16, 1024, 0, stream>>>(xgT, whh_bf + (size_t)l * 196608,
                                           bhh + l * 768, h0 + (size_t)l * 65536,
                                           (void*)OF);
    inl = (l < 5) ? outs[l] : inl;
    K = 256;
    W = wih_bf + (size_t)l * 196608;
  }
}

// Round 3
// 5522.869 us; speedup vs baseline: 4.9350x; 3.9977x over previous
//
#include <hip/hip_runtime.h>

typedef __bf16 bf16_t;
typedef __bf16 bf16x4 __attribute__((ext_vector_type(4)));
typedef __bf16 bf16x8 __attribute__((ext_vector_type(8)));
typedef float  f32x4  __attribute__((ext_vector_type(4)));

#define CT 32      // timesteps per chunk
#define NCHUNK 32  // chunks (1024 / CT)
#define NLAUNCH 43 // max G = 31 + 2*5 + 1 = 42

__device__ __forceinline__ float sigm_f(float x) {
  float e = __builtin_amdgcn_exp2f(x * -1.44269504f);
  return __builtin_amdgcn_rcpf(1.0f + e);
}
__device__ __forceinline__ float tanh_f(float x) {
  x = fminf(fmaxf(x, -15.0f), 15.0f);
  float e = __builtin_amdgcn_exp2f(x * -2.88539008f);
  float r = __builtin_amdgcn_rcpf(1.0f + e);
  return fmaf(-2.0f * e, r, 1.0f);
}
__device__ __forceinline__ float bf2f(unsigned u16) {
  union { unsigned u; float f; } v; v.u = u16 << 16; return v.f;
}

// ---------------------------------------------------------------- casts
__global__ void cast_f32_to_bf16(const float* __restrict__ src,
                                 bf16_t* __restrict__ dst, long n8) {
  long i = (long)blockIdx.x * blockDim.x + threadIdx.x;
  long stride = (long)gridDim.x * blockDim.x;
  for (; i < n8; i += stride) {
    const float4* sp = (const float4*)src + 2 * i;
    float4 a = sp[0], b = sp[1];
    bf16x8 v;
    v[0] = (bf16_t)a.x; v[1] = (bf16_t)a.y; v[2] = (bf16_t)a.z; v[3] = (bf16_t)a.w;
    v[4] = (bf16_t)b.x; v[5] = (bf16_t)b.y; v[6] = (bf16_t)b.z; v[7] = (bf16_t)b.w;
    ((bf16x8*)dst)[i] = v;
  }
}

// 4x4 bf16 transpose among the 4 lanes of a quad (lane bits 0..1), values
// packed 2-per-u32. In: lane q holds row q (A={c0,c1}, B={c2,c3}).
// Out: lane q holds col q (A={r0,r1}, B={r2,r3}).
__device__ __forceinline__ void quad_transpose(unsigned& A, unsigned& B, int q) {
  unsigned tA = __shfl_xor(A, 1);
  unsigned tB = __shfl_xor(B, 1);
  unsigned Ae = (A & 0xFFFFu) | (tA << 16);
  unsigned Ao = (tA >> 16) | (A & 0xFFFF0000u);
  unsigned Be = (B & 0xFFFFu) | (tB << 16);
  unsigned Bo = (tB >> 16) | (B & 0xFFFF0000u);
  unsigned A1 = (q & 1) ? Ao : Ae;
  unsigned B1 = (q & 1) ? Bo : Be;
  unsigned tA1 = __shfl_xor(A1, 2);
  unsigned tB1 = __shfl_xor(B1, 2);
  A = (q & 2) ? tB1 : A1;
  B = (q & 2) ? B1 : tA1;
}

// ---------------------------------------------------------------- wavefront
// grid = 256 x 1024 threads.
// bid <  96: SCAN role. l = bid>>4, s = bid&15, chunk c = G-2l-1.
// bid >= 96: GEMM role. jobs j = (l*3+... decoded below), chunk c = G-2l.
__global__ __launch_bounds__(1024) void wavefront(
    const bf16_t* __restrict__ x_bf,   // [1024][256][128]
    const bf16_t* __restrict__ wih0b,  // [768][128]
    const bf16_t* __restrict__ wihb,   // [5][768][256]
    const bf16_t* __restrict__ whhb,   // [6][768][256]
    const float* __restrict__ bih,     // [6][768]
    const float* __restrict__ bhh,     // [6][768]
    const float* __restrict__ h0,      // [6][256][256]
    bf16_t* __restrict__ xgring,       // [6][2][16][CT][768][16]
    bf16_t* __restrict__ hring,        // [5][2][CT][256][256]
    float* __restrict__ hstate,        // [96][16][256]
    float* __restrict__ out_f,         // [1024][256][256]
    int G) {
  __shared__ __align__(16) char lds_raw[49152];
  const int bid = blockIdx.x;
  const int tid = threadIdx.x;
  const int w = tid >> 6, ln = tid & 63;
  const int lq = ln >> 4, lr = ln & 15;

  if (bid < 96) {
    // ================= SCAN =================
    const int l = bid >> 4, s = bid & 15;
    const int c = G - 2 * l - 1;
    if (c < 0 || c >= NCHUNK) return;
    bf16_t* hs = (bf16_t*)lds_raw;  // [2][16][256] swizzled
    const int j = w * 16 + lr;

    bf16x8 wf[3][8];
#pragma unroll
    for (int gt = 0; gt < 3; ++gt) {
      const size_t g = (size_t)l * 196608 + (size_t)(gt * 256 + j) * 256;
#pragma unroll
      for (int kt = 0; kt < 8; ++kt)
        wf[gt][kt] = *(const bf16x8*)(whhb + g + kt * 32 + lq * 8);
    }
    const float bhn = bhh[l * 768 + 512 + j];

    float h[4];
#pragma unroll
    for (int r = 0; r < 4; ++r) {
      const int bl = lq * 4 + r;
      float v;
      if (c == 0) v = h0[(size_t)l * 65536 + (size_t)(s * 16 + bl) * 256 + j];
      else        v = hstate[(size_t)(l * 16 + s) * 4096 + bl * 256 + j];
      h[r] = v;
      hs[bl * 256 + ((((j >> 3) ^ (bl & 7)) << 3) | (j & 7))] = (bf16_t)v;
    }

    const bf16_t* xgp = xgring + ((size_t)((l * 2 + (c & 1)) * 16 + s)) * 393216
                        + j * 16 + lq * 4;
    // output bases
    bf16_t* rng = (l < 5)
        ? hring + (size_t)l * 4194304 + (size_t)(c & 1) * 2097152
        : (bf16_t*)0;
    float* ofp = (l == 5) ? out_f + (size_t)c * CT * 65536 : (float*)0;

    const int q = lr & 3, a4 = lr & 12;       // quad index, 4*a
    const int bq = lq * 4 + q;                 // post-transpose batch row
    const int jj = w * 16 + a4;                // post-transpose j base (x4)
    const int hswz = bq * 512 + ((((jj >> 3) ^ (bq & 7)) << 4) | ((jj & 7) * 2));

    __syncthreads();
    bf16x4 xa0 = *(const bf16x4*)(xgp);
    bf16x4 xa1 = *(const bf16x4*)(xgp + 4096);
    bf16x4 xa2 = *(const bf16x4*)(xgp + 8192);
    int rb = 0;
    for (int t = 0; t < CT; ++t) {
      bf16x4 nb0, nb1, nb2;
      if (t + 1 < CT) {
        const bf16_t* nx = xgp + (size_t)(t + 1) * 12288;
        nb0 = *(const bf16x4*)(nx);
        nb1 = *(const bf16x4*)(nx + 4096);
        nb2 = *(const bf16x4*)(nx + 8192);
      }
      f32x4 acc0 = {0.f, 0.f, 0.f, 0.f};
      f32x4 acc1 = {0.f, 0.f, 0.f, 0.f};
      f32x4 acc2 = {0.f, 0.f, 0.f, 0.f};
      const bf16_t* hb = hs + rb * 4096;
#pragma unroll
      for (int kt = 0; kt < 8; ++kt) {
        const bf16x8 a =
            *(const bf16x8*)&hb[lr * 256 + (((kt * 4 + lq) ^ (lr & 7)) << 3)];
        acc0 = __builtin_amdgcn_mfma_f32_16x16x32_bf16(a, wf[0][kt], acc0, 0, 0, 0);
        acc1 = __builtin_amdgcn_mfma_f32_16x16x32_bf16(a, wf[1][kt], acc1, 0, 0, 0);
        acc2 = __builtin_amdgcn_mfma_f32_16x16x32_bf16(a, wf[2][kt], acc2, 0, 0, 0);
      }
#pragma unroll
      for (int r = 0; r < 4; ++r) {
        const float rg = sigm_f((float)xa0[r] + acc0[r]);
        const float zg = sigm_f((float)xa1[r] + acc1[r]);
        const float nn = tanh_f((float)xa2[r] + rg * (acc2[r] + bhn));
        h[r] = nn + zg * (h[r] - nn);
      }
      unsigned P0, P1;
      asm volatile("v_cvt_pk_bf16_f32 %0, %1, %2" : "=v"(P0) : "v"(h[0]), "v"(h[1]));
      asm volatile("v_cvt_pk_bf16_f32 %0, %1, %2" : "=v"(P1) : "v"(h[2]), "v"(h[3]));
      quad_transpose(P0, P1, q);
      // hs write: one conflict-light b64 per lane
      char* hw = (char*)(hs + (1 - rb) * 4096);
      uint2 pk; pk.x = P0; pk.y = P1;
      *(uint2*)(hw + hswz) = pk;
      // global out
      if (l < 5) {
        *(uint2*)(rng + ((size_t)t * 256 + s * 16 + bq) * 256 + jj) = pk;
      } else {
        float4 o;
        o.x = bf2f(P0 & 0xFFFFu); o.y = bf2f(P0 >> 16);
        o.z = bf2f(P1 & 0xFFFFu); o.w = bf2f(P1 >> 16);
        *(float4*)(ofp + ((size_t)t * 256 + s * 16 + bq) * 256 + jj) = o;
      }
      __syncthreads();
      rb ^= 1;
      xa0 = nb0; xa1 = nb1; xa2 = nb2;
    }
    // persist h state (fp32, pre-transpose ownership)
#pragma unroll
    for (int r = 0; r < 4; ++r)
      hstate[(size_t)(l * 16 + s) * 4096 + (lq * 4 + r) * 256 + j] = h[r];
  } else {
    // ================= GEMM (xg for chunk c = G - 2l) =================
    bf16_t* As = (bf16_t*)lds_raw;            // [128][64]
    bf16_t* Bs = (bf16_t*)(lds_raw + 16384);  // [256][64]
    const int aid = bid - 96;
    const int wm = w >> 3, wn = w & 7;
    for (int job = aid; job < 1152; job += 160) {
      const int l = job / 192;
      const int c = G - 2 * l;
      if (c < 0 || c >= NCHUNK) continue;
      const int rem = job % 192;
      const int s = rem & 15, mt = (rem >> 4) & 3, nt = rem >> 6;
      const int K = (l == 0) ? 128 : 256;
      const bf16_t* Ab = (l == 0)
          ? x_bf + (size_t)c * CT * 32768
          : hring + (size_t)(l - 1) * 4194304 + (size_t)(c & 1) * 2097152;
      const bf16_t* Wb = (l == 0) ? wih0b : wihb + (size_t)(l - 1) * 196608;
      const float* bi_p = bih + l * 768;
      const float* bh_p = bhh + l * 768;
      bf16_t* Cg = xgring + ((size_t)((l * 2 + (c & 1)) * 16 + s)) * 393216;

      f32x4 acc[4][2];
      f32x4 zf = {0.f, 0.f, 0.f, 0.f};
#pragma unroll
      for (int mi = 0; mi < 4; ++mi) { acc[mi][0] = zf; acc[mi][1] = zf; }

      const int rl = tid >> 3, seg = tid & 7;
      for (int kb = 0; kb < K; kb += 64) {
        {  // stage A tile [128 rows][64 k]
          const int cb = (seg * 16) ^ ((rl & 7) << 4);
          const int R = mt * 128 + rl;
          const int t = R >> 4, b = s * 16 + (R & 15);
          const bf16_t* ga = Ab + ((size_t)t * 256 + b) * K + kb + (cb >> 1);
          __builtin_amdgcn_global_load_lds(
              (const __attribute__((address_space(1))) void*)ga,
              (__attribute__((address_space(3))) void*)((char*)As + rl * 128 + seg * 16),
              16, 0, 0);
        }
#pragma unroll
        for (int cc = 0; cc < 2; ++cc) {  // stage B tile [256 gates][64 k]
          const int rw = cc * 128 + rl;
          const int cb = (seg * 16) ^ ((rw & 7) << 4);
          const bf16_t* gb = Wb + (size_t)(nt * 256 + rw) * K + kb + (cb >> 1);
          __builtin_amdgcn_global_load_lds(
              (const __attribute__((address_space(1))) void*)gb,
              (__attribute__((address_space(3))) void*)((char*)Bs + rw * 128 + seg * 16),
              16, 0, 0);
        }
        __syncthreads();
#pragma unroll
        for (int ks = 0; ks < 2; ++ks) {
          bf16x8 av[4], bv[2];
#pragma unroll
          for (int mi = 0; mi < 4; ++mi) {
            const int row = wm * 64 + mi * 16 + lr;
            const int cb = (ks * 64 + lq * 16) ^ ((row & 7) << 4);
            av[mi] = *(const bf16x8*)((const char*)As + row * 128 + cb);
          }
#pragma unroll
          for (int ni = 0; ni < 2; ++ni) {
            const int row = wn * 32 + ni * 16 + lr;
            const int cb = (ks * 64 + lq * 16) ^ ((row & 7) << 4);
            bv[ni] = *(const bf16x8*)((const char*)Bs + row * 128 + cb);
          }
#pragma unroll
          for (int mi = 0; mi < 4; ++mi)
#pragma unroll
            for (int ni = 0; ni < 2; ++ni)
              acc[mi][ni] = __builtin_amdgcn_mfma_f32_16x16x32_bf16(
                  av[mi], bv[ni], acc[mi][ni], 0, 0, 0);
        }
        __syncthreads();
      }
      // epilogue: bias + bf16, write to xg ring layout [t][768][16]
#pragma unroll
      for (int ni = 0; ni < 2; ++ni) {
        const int g = nt * 256 + wn * 32 + ni * 16 + lr;
        const float bi = bi_p[g] + (g < 512 ? bh_p[g] : 0.0f);
#pragma unroll
        for (int mi = 0; mi < 4; ++mi) {
          const int t = mt * 8 + wm * 4 + mi;
          bf16x4 v;
#pragma unroll
          for (int r = 0; r < 4; ++r) v[r] = (bf16_t)(acc[mi][ni][r] + bi);
          *(bf16x4*)&Cg[(size_t)t * 12288 + g * 16 + lq * 4] = v;
        }
      }
    }
  }
}

// ---------------------------------------------------------------- launch
extern "C" void kernel_launch(void* const* d_in, const int* in_sizes, int n_in,
                              void* d_out, int out_size, void* d_ws, size_t ws_size,
                              hipStream_t stream) {
  const float* x    = (const float*)d_in[0];
  const float* h0   = (const float*)d_in[1];
  const float* wih0 = (const float*)d_in[2];
  const float* wih  = (const float*)d_in[3];
  const float* whh  = (const float*)d_in[4];
  const float* bih  = (const float*)d_in[5];
  const float* bhh  = (const float*)d_in[6];

  // ws layout (bytes):
  //  xgring  [6][2][16][32][768][16] bf16 : 150,994,944
  //  hring   [5][2][32][256][256]    bf16 :  41,943,040
  //  x_bf    [1024][256][128]        bf16 :  67,108,864
  //  whh_bf  [6][768][256]           bf16 :   2,359,296
  //  wih0_bf [768][128]              bf16 :     196,608
  //  wih_bf  [5][768][256]           bf16 :   1,966,080
  //  hstate  [96][16][256]           f32  :   1,572,864
  char* ws = (char*)d_ws;
  bf16_t* xgring  = (bf16_t*)(ws);
  bf16_t* hringp  = (bf16_t*)(ws + 150994944ull);
  bf16_t* x_bf    = (bf16_t*)(ws + 192937984ull);
  bf16_t* whh_bf  = (bf16_t*)(ws + 260046848ull);
  bf16_t* wih0_bf = (bf16_t*)(ws + 262406144ull);
  bf16_t* wih_bf  = (bf16_t*)(ws + 262602752ull);
  float*  hstate  = (float*)(ws + 264568832ull);

  cast_f32_to_bf16<<<2048, 256, 0, stream>>>(x, x_bf, 4194304L);
  cast_f32_to_bf16<<<576, 256, 0, stream>>>(whh, whh_bf, 147456L);
  cast_f32_to_bf16<<<48, 256, 0, stream>>>(wih0, wih0_bf, 12288L);
  cast_f32_to_bf16<<<480, 256, 0, stream>>>(wih, wih_bf, 122880L);

  for (int G = 0; G < NLAUNCH; ++G) {
    wavefront<<<256, 1024, 0, stream>>>(x_bf, wih0_bf, wih_bf, whh_bf,
                                        bih, bhh, h0, xgring, hringp, hstate,
                                        (float*)d_out, G);
  }
}